// Round 1
// baseline (112.102 us; speedup 1.0000x reference)
//
#include <hip/hip_runtime.h>

#define NROWS 1024
#define X1D 256
#define X2D 128
#define HID 256
#define ROWS 8   // rows per block in fused kernel

// ---------------- K1: column stats of x2: sums[d] = sum_i x2[i][d], sums[128+d] = sum_i x2[i][d]^2
__global__ __launch_bounds__(256) void stats_kernel(const float* __restrict__ x2,
                                                    float* __restrict__ sums) {
    int tid = threadIdx.x;
    int d = tid & 127;
    int g = tid >> 7;                       // 0 or 1
    int row0 = blockIdx.x * 128 + g;        // 8 blocks, 128 rows each
    float s = 0.f, s2 = 0.f;
#pragma unroll 8
    for (int i = 0; i < 64; i++) {
        float v = x2[(row0 + 2 * i) * X2D + d];
        s += v;
        s2 += v * v;
    }
    __shared__ float sh[256];
    __shared__ float sh2[256];
    sh[tid] = s;
    sh2[tid] = s2;
    __syncthreads();
    if (g == 0) {
        atomicAdd(&sums[d], sh[tid] + sh[tid + 128]);
        atomicAdd(&sums[128 + d], sh2[tid] + sh2[tid + 128]);
    }
}

// ---------------- fused MLP layer: out[r][c] = act(b[c] + sum_k in[r][k]*W[k][c])
// thread c owns column c for all ROWS rows. W loads coalesced (lane c -> W[k*256+c]).
// x reads are wave-uniform LDS broadcasts (ds_read_b128, conflict-free).
__device__ __forceinline__ void layer256(const float* __restrict__ in_lds,
                                         const float* __restrict__ W,
                                         const float* __restrict__ b,
                                         float* __restrict__ out_lds,
                                         int c, int act /*0=relu,1=tanh*/) {
    float acc[ROWS];
    float bias = b[c];
#pragma unroll
    for (int r = 0; r < ROWS; r++) acc[r] = bias;
    const float4* in4 = (const float4*)in_lds;
    for (int k = 0; k < 256; k += 4) {
        float w0 = W[(k + 0) * 256 + c];
        float w1 = W[(k + 1) * 256 + c];
        float w2 = W[(k + 2) * 256 + c];
        float w3 = W[(k + 3) * 256 + c];
#pragma unroll
        for (int r = 0; r < ROWS; r++) {
            float4 xv = in4[r * 64 + (k >> 2)];
            acc[r] = fmaf(xv.x, w0, acc[r]);
            acc[r] = fmaf(xv.y, w1, acc[r]);
            acc[r] = fmaf(xv.z, w2, acc[r]);
            acc[r] = fmaf(xv.w, w3, acc[r]);
        }
    }
#pragma unroll
    for (int r = 0; r < ROWS; r++) {
        float v = acc[r];
        v = (act == 0) ? fmaxf(v, 0.f) : tanhf(v);
        out_lds[r * 256 + c] = v;
    }
}

// ---------------- K2: fused 3-layer MLP + CLUB contribution + reduction
__global__ __launch_bounds__(256) void club_kernel(
    const float* __restrict__ x1, const float* __restrict__ x2,
    const float* __restrict__ W1, const float* __restrict__ b1,
    const float* __restrict__ W2, const float* __restrict__ b2,
    const float* __restrict__ W3, const float* __restrict__ b3,
    const float* __restrict__ sums, float* __restrict__ out) {
    __shared__ float bufA[ROWS * 256];
    __shared__ float bufB[ROWS * 256];
    __shared__ float x2s[ROWS * 128];
    __shared__ double red[4];

    int tid = threadIdx.x;
    int row0 = blockIdx.x * ROWS;

    // stage x1 tile (2048 floats) and x2 tile (1024 floats) into LDS, coalesced float4
    {
        const float4* s1 = (const float4*)(x1 + row0 * X1D);
        float4* dA = (float4*)bufA;
        dA[tid] = s1[tid];
        dA[tid + 256] = s1[tid + 256];
        const float4* s2p = (const float4*)(x2 + row0 * X2D);
        float4* dX = (float4*)x2s;
        dX[tid] = s2p[tid];
    }
    __syncthreads();

    layer256(bufA, W1, b1, bufB, tid, 0);   // h1 = relu(x1@W1+b1)
    __syncthreads();
    layer256(bufB, W2, b2, bufA, tid, 0);   // h2 = relu(h1@W2+b2)
    __syncthreads();
    layer256(bufA, W3, b3, bufB, tid, 1);   // g  = tanh(h2@W3+b3) = [mu | logvar]
    __syncthreads();

    // per-element contribution:
    //  pos - neg = -0.5*exp(-lv) * ( x2^2 - mxsq - 2*mu*(x2 - mx) )
    int d = tid & 127;
    int g2 = tid >> 7;
    double mx = (double)sums[d] * (1.0 / 1024.0);
    double mxsq = (double)sums[128 + d] * (1.0 / 1024.0);
    double p = 0.0;
#pragma unroll
    for (int i = 0; i < ROWS / 2; i++) {
        int r = g2 + 2 * i;
        double mu = (double)bufB[r * 256 + d];
        double lv = (double)bufB[r * 256 + 128 + d];
        double xv = (double)x2s[r * 128 + d];
        double iv = exp(-lv);
        p += -0.5 * iv * (xv * xv - mxsq - 2.0 * mu * (xv - mx));
    }
    // wave (64) shuffle reduce, then cross-wave via LDS
#pragma unroll
    for (int off = 32; off > 0; off >>= 1) p += __shfl_down(p, off, 64);
    int lane = tid & 63, wv = tid >> 6;
    if (lane == 0) red[wv] = p;
    __syncthreads();
    if (tid == 0) {
        double s = red[0] + red[1] + red[2] + red[3];
        atomicAdd(out, (float)(s * (1.0 / 1024.0)));
    }
}

extern "C" void kernel_launch(void* const* d_in, const int* in_sizes, int n_in,
                              void* d_out, int out_size, void* d_ws, size_t ws_size,
                              hipStream_t stream) {
    const float* x1 = (const float*)d_in[0];
    const float* x2 = (const float*)d_in[1];
    const float* W1 = (const float*)d_in[2];
    const float* b1 = (const float*)d_in[3];
    const float* W2 = (const float*)d_in[4];
    const float* b2 = (const float*)d_in[5];
    const float* W3 = (const float*)d_in[6];
    const float* b3 = (const float*)d_in[7];
    float* out = (float*)d_out;
    float* sums = (float*)d_ws;   // 256 floats: [0..127]=sum x2, [128..255]=sum x2^2

    hipMemsetAsync(sums, 0, 256 * sizeof(float), stream);
    hipMemsetAsync(out, 0, sizeof(float), stream);
    stats_kernel<<<8, 256, 0, stream>>>(x2, sums);
    club_kernel<<<NROWS / ROWS, 256, 0, stream>>>(x1, x2, W1, b1, W2, b2, W3, b3, sums, out);
}

// Round 2
// 91.292 us; speedup vs baseline: 1.2279x; 1.2279x over previous
//
#include <hip/hip_runtime.h>

#define NR 1024
#define ROWS 4
#define NBLK (NR / ROWS)   // 256 blocks = 1 per CU
#define NTHR 1024          // 256 cols x 4 k-quarters

// ---------------- K1: 8 blocks x 256 thr. Partial column sums of x2 / x2^2
// written to disjoint ws slots (no atomics -> no memset dispatch needed).
// Block 0 thread 0 also zeroes d_out (club atomicAdds after, stream-ordered).
__global__ __launch_bounds__(256) void stats_kernel(const float* __restrict__ x2,
                                                    float* __restrict__ ws,
                                                    float* __restrict__ out) {
    int tid = threadIdx.x;
    int d = tid & 127;
    int g = tid >> 7;                    // 0 or 1
    int row0 = blockIdx.x * 128 + g;
    float s = 0.f, s2 = 0.f;
#pragma unroll 8
    for (int i = 0; i < 64; i++) {
        float v = x2[(row0 + 2 * i) * 128 + d];
        s += v;
        s2 += v * v;
    }
    __shared__ float sh[256];
    __shared__ float sh2[256];
    sh[tid] = s;
    sh2[tid] = s2;
    __syncthreads();
    if (g == 0) {
        ws[blockIdx.x * 256 + d]       = sh[tid] + sh[tid + 128];
        ws[blockIdx.x * 256 + 128 + d] = sh2[tid] + sh2[tid + 128];
    }
    if (blockIdx.x == 0 && tid == 0) out[0] = 0.f;
}

// ---------------- fused layer, k-split 4 ways.
// thread (c, h) accumulates k in [h*64, h*64+64) for 4 rows; LDS reduce.
__device__ __forceinline__ void layer(const float* __restrict__ in_lds,
                                      const float* __restrict__ W,
                                      const float* __restrict__ b,
                                      float* __restrict__ out_lds,
                                      float* __restrict__ red,
                                      int tid, int c, int h, int act) {
    const float* Wp = W + c;                   // W[k][c] at Wp[k*256]
    const float4* in4 = (const float4*)in_lds; // row r = 64 float4s
    float a0 = 0.f, a1 = 0.f, a2 = 0.f, a3 = 0.f;
    int kb = h * 64;
#pragma unroll
    for (int s = 0; s < 16; s++) {
        int k = kb + s * 4;
        float w0 = Wp[(k + 0) * 256];
        float w1 = Wp[(k + 1) * 256];
        float w2 = Wp[(k + 2) * 256];
        float w3 = Wp[(k + 3) * 256];
        float4 xa = in4[0 * 64 + (k >> 2)];   // wave-uniform LDS broadcasts
        float4 xb = in4[1 * 64 + (k >> 2)];
        float4 xc = in4[2 * 64 + (k >> 2)];
        float4 xd = in4[3 * 64 + (k >> 2)];
        a0 = fmaf(xa.x, w0, a0); a0 = fmaf(xa.y, w1, a0); a0 = fmaf(xa.z, w2, a0); a0 = fmaf(xa.w, w3, a0);
        a1 = fmaf(xb.x, w0, a1); a1 = fmaf(xb.y, w1, a1); a1 = fmaf(xb.z, w2, a1); a1 = fmaf(xb.w, w3, a1);
        a2 = fmaf(xc.x, w0, a2); a2 = fmaf(xc.y, w1, a2); a2 = fmaf(xc.z, w2, a2); a2 = fmaf(xc.w, w3, a2);
        a3 = fmaf(xd.x, w0, a3); a3 = fmaf(xd.y, w1, a3); a3 = fmaf(xd.z, w2, a3); a3 = fmaf(xd.w, w3, a3);
    }
    float4 v; v.x = a0; v.y = a1; v.z = a2; v.w = a3;
    ((float4*)red)[tid] = v;
    __syncthreads();
    if (h == 0) {
        float bias = b[c];
        float4 s0 = ((float4*)red)[c];
        float4 s1 = ((float4*)red)[c + 256];
        float4 s2 = ((float4*)red)[c + 512];
        float4 s3 = ((float4*)red)[c + 768];
        float r0 = bias + s0.x + s1.x + s2.x + s3.x;
        float r1 = bias + s0.y + s1.y + s2.y + s3.y;
        float r2 = bias + s0.z + s1.z + s2.z + s3.z;
        float r3 = bias + s0.w + s1.w + s2.w + s3.w;
        if (act == 0) {
            r0 = fmaxf(r0, 0.f); r1 = fmaxf(r1, 0.f);
            r2 = fmaxf(r2, 0.f); r3 = fmaxf(r3, 0.f);
        } else {
            r0 = tanhf(r0); r1 = tanhf(r1); r2 = tanhf(r2); r3 = tanhf(r3);
        }
        out_lds[0 * 256 + c] = r0;
        out_lds[1 * 256 + c] = r1;
        out_lds[2 * 256 + c] = r2;
        out_lds[3 * 256 + c] = r3;
    }
    __syncthreads();
}

// ---------------- K2: fused 3-layer MLP + CLUB contribution + reduction
__global__ __launch_bounds__(1024, 4) void club_kernel(
    const float* __restrict__ x1, const float* __restrict__ x2,
    const float* __restrict__ W1, const float* __restrict__ b1,
    const float* __restrict__ W2, const float* __restrict__ b2,
    const float* __restrict__ W3, const float* __restrict__ b3,
    const float* __restrict__ part, float* __restrict__ out) {
    __shared__ float bufA[ROWS * 256];
    __shared__ float bufB[ROWS * 256];
    __shared__ float x2s[ROWS * 128];
    __shared__ float stat[256];        // [0..127]=col mean, [128..255]=col meansq
    __shared__ float red[NTHR * 4];    // 16 KB k-split partials
    __shared__ double dred[16];

    int tid = threadIdx.x;
    int c = tid & 255;
    int h = tid >> 8;                  // k-quarter 0..3
    int row0 = blockIdx.x * ROWS;

    // prologue: stage x1 (4x256), x2 (4x128) tiles; reduce the 8 stats partials
    if (tid < 256) {
        ((float4*)bufA)[tid] = ((const float4*)(x1 + row0 * 256))[tid];
    } else if (tid < 384) {
        ((float4*)x2s)[tid - 256] = ((const float4*)(x2 + row0 * 128))[tid - 256];
    } else if (tid >= 512 && tid < 768) {
        int t = tid - 512;
        float s = 0.f;
#pragma unroll
        for (int p = 0; p < 8; p++) s += part[p * 256 + t];
        stat[t] = s * (1.f / 1024.f);
    }
    __syncthreads();

    layer(bufA, W1, b1, bufB, red, tid, c, h, 0);   // h1 = relu(x1@W1+b1)
    layer(bufB, W2, b2, bufA, red, tid, c, h, 0);   // h2 = relu(h1@W2+b2)
    layer(bufA, W3, b3, bufB, red, tid, c, h, 1);   // g  = tanh(h2@W3+b3)

    // contribution: pos-neg = -0.5*exp(-lv)*( x2^2 - mxsq - 2*mu*(x2 - mx) )
    double p = 0.0;
    if (tid < 512) {
        int d = tid & 127;
        int r = tid >> 7;
        double mu = (double)bufB[r * 256 + d];
        double lv = (double)bufB[r * 256 + 128 + d];
        double xv = (double)x2s[r * 128 + d];
        double mx = (double)stat[d];
        double mxsq = (double)stat[128 + d];
        double iv = exp(-lv);
        p = -0.5 * iv * (xv * xv - mxsq - 2.0 * mu * (xv - mx));
    }
#pragma unroll
    for (int off = 32; off > 0; off >>= 1) p += __shfl_down(p, off, 64);
    int lane = tid & 63, wv = tid >> 6;
    if (lane == 0) dred[wv] = p;
    __syncthreads();
    if (tid == 0) {
        double s = 0.0;
#pragma unroll
        for (int i = 0; i < 16; i++) s += dred[i];
        atomicAdd(out, (float)(s * (1.0 / 1024.0)));
    }
}

extern "C" void kernel_launch(void* const* d_in, const int* in_sizes, int n_in,
                              void* d_out, int out_size, void* d_ws, size_t ws_size,
                              hipStream_t stream) {
    const float* x1 = (const float*)d_in[0];
    const float* x2 = (const float*)d_in[1];
    const float* W1 = (const float*)d_in[2];
    const float* b1 = (const float*)d_in[3];
    const float* W2 = (const float*)d_in[4];
    const float* b2 = (const float*)d_in[5];
    const float* W3 = (const float*)d_in[6];
    const float* b3 = (const float*)d_in[7];
    float* out = (float*)d_out;
    float* ws = (float*)d_ws;   // 8 blocks x 256 floats of column partials

    stats_kernel<<<8, 256, 0, stream>>>(x2, ws, out);
    club_kernel<<<NBLK, NTHR, 0, stream>>>(x1, x2, W1, b1, W2, b2, W3, b3, ws, out);
}